// Round 17
// baseline (346.873 us; speedup 1.0000x reference)
//
#include <hip/hip_runtime.h>

#define NN 50000
#define NE 800000
#define GB 391     // ceil(NN/128) gemm node-blocks
#define NBUK 196   // dst buckets (dst>>8)
#define PB 128     // partition blocks
#define CH 6250    // edges per partition block (PB*CH == NE)
#define HLEN (NBUK * PB)       // 25088
#define SAB (HLEN / 256)       // 98 scan blocks

typedef __attribute__((ext_vector_type(8))) short short8v;
typedef __attribute__((ext_vector_type(4))) float float4v;

__device__ __forceinline__ int uni(int v) { return __builtin_amdgcn_readfirstlane(v); }
__device__ __forceinline__ unsigned short f2bf(float f) {
    unsigned u = __float_as_uint(f);
    return (unsigned short)((u + 0x7FFFu + ((u >> 16) & 1u)) >> 16);
}
__device__ __forceinline__ float bf2f(unsigned short h) {
    return __uint_as_float(((unsigned)h) << 16);
}

// ================= radix CSR build =================
__global__ __launch_bounds__(256) void hist_kernel(const int* __restrict__ dst,
                                                   int* __restrict__ H) {
    __shared__ int h[NBUK];
    const int t = threadIdx.x;
    const int b = blockIdx.x;
    if (t < NBUK) h[t] = 0;
    __syncthreads();
    const int e0 = b * CH;
    for (int i = t; i < CH; i += 256) {
        int e = e0 + i;
        if (e < NE) atomicAdd(&h[dst[e] >> 8], 1);
    }
    __syncthreads();
    if (t < NBUK) H[t * PB + b] = h[t];
}

__global__ __launch_bounds__(256) void scanA_kernel(const int* __restrict__ a,
                                                    int* __restrict__ part) {
    __shared__ int red[256];
    const int t = threadIdx.x;
    red[t] = a[blockIdx.x * 256 + t];
    __syncthreads();
#pragma unroll
    for (int d = 128; d > 0; d >>= 1) {
        if (t < d) red[t] += red[t + d];
        __syncthreads();
    }
    if (t == 0) part[blockIdx.x] = red[0];
}

__global__ __launch_bounds__(128) void scanB_kernel(int* __restrict__ part) {
    __shared__ int ps[128];
    const int t = threadIdx.x;
    ps[t] = (t < SAB) ? part[t] : 0;
    __syncthreads();
#pragma unroll
    for (int d = 1; d < 128; d <<= 1) {
        int v = (t >= d) ? ps[t - d] : 0;
        __syncthreads();
        ps[t] += v;
        __syncthreads();
    }
    if (t < SAB) part[t] = (t == 0) ? 0 : ps[t - 1];
}

__global__ __launch_bounds__(256) void scanC_kernel(int* __restrict__ a,
                                                    const int* __restrict__ part) {
    __shared__ int ps[256];
    const int t = threadIdx.x;
    const int i = blockIdx.x * 256 + t;
    const int c = a[i];
    ps[t] = c;
    __syncthreads();
#pragma unroll
    for (int d = 1; d < 256; d <<= 1) {
        int v = (t >= d) ? ps[t - d] : 0;
        __syncthreads();
        ps[t] += v;
        __syncthreads();
    }
    a[i] = part[blockIdx.x] + ps[t] - c;   // exclusive
}

__global__ __launch_bounds__(256) void partition_kernel(const int* __restrict__ src,
                                                        const int* __restrict__ dst,
                                                        const int* __restrict__ Hs,
                                                        unsigned* __restrict__ tmp) {
    __shared__ int cur[NBUK];
    const int t = threadIdx.x;
    const int b = blockIdx.x;
    if (t < NBUK) cur[t] = Hs[t * PB + b];
    __syncthreads();
    const int e0 = b * CH;
    for (int i = t; i < CH; i += 256) {
        int e = e0 + i;
        if (e < NE) {
            const int d = dst[e];
            const int k = d >> 8;
            const int pos = atomicAdd(&cur[k], 1);
            tmp[pos] = (unsigned)src[e] | ((unsigned)(d & 255) << 16);
        }
    }
}

__global__ __launch_bounds__(256) void finalize_kernel(const unsigned* __restrict__ tmp,
                                                       const int* __restrict__ Hs,
                                                       int* __restrict__ off,
                                                       int* __restrict__ cnt,
                                                       float* __restrict__ inv,
                                                       unsigned short* __restrict__ srcs) {
    __shared__ int hist[256];
    __shared__ int ps[256];
    __shared__ int cur[256];
    const int t = threadIdx.x;
    const int k = blockIdx.x;
    const int s0 = Hs[k * PB];
    const int end = (k == NBUK - 1) ? NE : Hs[(k + 1) * PB];
    const int m = end - s0;
    hist[t] = 0;
    __syncthreads();
    for (int i = t; i < m; i += 256) {
        atomicAdd(&hist[(tmp[s0 + i] >> 16) & 255], 1);
    }
    __syncthreads();
    const int c = hist[t];
    ps[t] = c;
    __syncthreads();
#pragma unroll
    for (int d = 1; d < 256; d <<= 1) {
        int v = (t >= d) ? ps[t - d] : 0;
        __syncthreads();
        ps[t] += v;
        __syncthreads();
    }
    const int ex = ps[t] - c;
    const int node = k * 256 + t;
    if (node < NN) {
        off[node] = s0 + ex;
        cnt[node] = c;
        inv[node] = 1.0f / (float)max(c, 1);
    }
    cur[t] = s0 + ex;
    __syncthreads();
    for (int i = t; i < m; i += 256) {
        const unsigned u = tmp[s0 + i];
        const int p = atomicAdd(&cur[(u >> 16) & 255], 1);
        srcs[p] = (unsigned short)(u & 0xFFFFu);
    }
}

// ================= pull-gather mean aggregation (half-wave per edge) =================
// MODE: 0 = mean ; 1 = relu(pre + mean) ; 2 = pre + mean
// PLANES: write result as bf16 hi/lo planes (outh/outl, stride os2) instead of fp32 out.
template<int D, int MODE, int PLANES>
__global__ __launch_bounds__(256) void gather_kernel(
    const unsigned short* __restrict__ yb, int ys, const unsigned short* __restrict__ srcs,
    const int* __restrict__ off, const int* __restrict__ cnt,
    const float* __restrict__ inv, const float* __restrict__ pre, int ps,
    float* __restrict__ out, int os,
    unsigned short* __restrict__ outh, unsigned short* __restrict__ outl, int os2) {
    const int w = (blockIdx.x * blockDim.x + threadIdx.x) >> 6;
    const int lane = threadIdx.x & 63;
    if (w >= NN) return;
    const int o = uni(off[w]);
    const int n = uni(cnt[w]);
    const int h = lane >> 5;       // half-wave id
    const int l = lane & 31;

    float a0 = 0.0f, a1 = 0.0f, a2 = 0.0f, a3 = 0.0f;
    int i = 0;
    for (; i + 8 <= n; i += 8) {
        int e0 = srcs[o + i + h];
        int e1 = srcs[o + i + 2 + h];
        int e2 = srcs[o + i + 4 + h];
        int e3 = srcs[o + i + 6 + h];
        if constexpr (D == 64) {
            const ushort2 v0 = *reinterpret_cast<const ushort2*>(&yb[(size_t)e0 * ys + 2 * l]);
            const ushort2 v1 = *reinterpret_cast<const ushort2*>(&yb[(size_t)e1 * ys + 2 * l]);
            const ushort2 v2 = *reinterpret_cast<const ushort2*>(&yb[(size_t)e2 * ys + 2 * l]);
            const ushort2 v3 = *reinterpret_cast<const ushort2*>(&yb[(size_t)e3 * ys + 2 * l]);
            a0 += bf2f(v0.x) + bf2f(v1.x) + bf2f(v2.x) + bf2f(v3.x);
            a1 += bf2f(v0.y) + bf2f(v1.y) + bf2f(v2.y) + bf2f(v3.y);
        } else {
            const ushort4 v0 = *reinterpret_cast<const ushort4*>(&yb[(size_t)e0 * ys + 4 * l]);
            const ushort4 v1 = *reinterpret_cast<const ushort4*>(&yb[(size_t)e1 * ys + 4 * l]);
            const ushort4 v2 = *reinterpret_cast<const ushort4*>(&yb[(size_t)e2 * ys + 4 * l]);
            const ushort4 v3 = *reinterpret_cast<const ushort4*>(&yb[(size_t)e3 * ys + 4 * l]);
            a0 += bf2f(v0.x) + bf2f(v1.x) + bf2f(v2.x) + bf2f(v3.x);
            a1 += bf2f(v0.y) + bf2f(v1.y) + bf2f(v2.y) + bf2f(v3.y);
            a2 += bf2f(v0.z) + bf2f(v1.z) + bf2f(v2.z) + bf2f(v3.z);
            a3 += bf2f(v0.w) + bf2f(v1.w) + bf2f(v2.w) + bf2f(v3.w);
        }
    }
    for (; i + 2 <= n; i += 2) {
        int e = srcs[o + i + h];
        if constexpr (D == 64) {
            const ushort2 v = *reinterpret_cast<const ushort2*>(&yb[(size_t)e * ys + 2 * l]);
            a0 += bf2f(v.x);
            a1 += bf2f(v.y);
        } else {
            const ushort4 v = *reinterpret_cast<const ushort4*>(&yb[(size_t)e * ys + 4 * l]);
            a0 += bf2f(v.x); a1 += bf2f(v.y); a2 += bf2f(v.z); a3 += bf2f(v.w);
        }
    }
    if (i < n && h == 0) {
        int e = srcs[o + i];
        if constexpr (D == 64) {
            const ushort2 v = *reinterpret_cast<const ushort2*>(&yb[(size_t)e * ys + 2 * l]);
            a0 += bf2f(v.x);
            a1 += bf2f(v.y);
        } else {
            const ushort4 v = *reinterpret_cast<const ushort4*>(&yb[(size_t)e * ys + 4 * l]);
            a0 += bf2f(v.x); a1 += bf2f(v.y); a2 += bf2f(v.z); a3 += bf2f(v.w);
        }
    }
    // combine halves
    a0 += __shfl_xor(a0, 32, 64);
    a1 += __shfl_xor(a1, 32, 64);
    if constexpr (D == 128) {
        a2 += __shfl_xor(a2, 32, 64);
        a3 += __shfl_xor(a3, 32, 64);
    }
    if (h != 0) return;

    const float iv = inv[w];
    if constexpr (D == 64) {
        float r0 = a0 * iv, r1 = a1 * iv;
        if constexpr (MODE != 0) {
            const float2 pv = *reinterpret_cast<const float2*>(&pre[(size_t)w * ps + 2 * l]);
            r0 += pv.x; r1 += pv.y;
        }
        if constexpr (MODE == 1) { r0 = fmaxf(r0, 0.0f); r1 = fmaxf(r1, 0.0f); }
        if constexpr (PLANES) {
            const unsigned short h0 = f2bf(r0), h1v = f2bf(r1);
            ushort2 hv = {h0, h1v};
            ushort2 lv = {f2bf(r0 - bf2f(h0)), f2bf(r1 - bf2f(h1v))};
            *reinterpret_cast<ushort2*>(&outh[(size_t)w * os2 + 2 * l]) = hv;
            *reinterpret_cast<ushort2*>(&outl[(size_t)w * os2 + 2 * l]) = lv;
        } else {
            float2 sv = {r0, r1};
            *reinterpret_cast<float2*>(&out[(size_t)w * os + 2 * l]) = sv;
        }
    } else {
        float r0 = a0 * iv, r1 = a1 * iv, r2 = a2 * iv, r3 = a3 * iv;
        if constexpr (MODE != 0) {
            const float4 pv = *reinterpret_cast<const float4*>(&pre[(size_t)w * ps + 4 * l]);
            r0 += pv.x; r1 += pv.y; r2 += pv.z; r3 += pv.w;
        }
        if constexpr (MODE == 1) {
            r0 = fmaxf(r0, 0.0f); r1 = fmaxf(r1, 0.0f);
            r2 = fmaxf(r2, 0.0f); r3 = fmaxf(r3, 0.0f);
        }
        if constexpr (PLANES) {
            const unsigned short h0 = f2bf(r0), h1v = f2bf(r1), h2 = f2bf(r2), h3 = f2bf(r3);
            ushort4 hv = {h0, h1v, h2, h3};
            ushort4 lv = {f2bf(r0 - bf2f(h0)), f2bf(r1 - bf2f(h1v)),
                          f2bf(r2 - bf2f(h2)), f2bf(r3 - bf2f(h3))};
            *reinterpret_cast<ushort4*>(&outh[(size_t)w * os2 + 4 * l]) = hv;
            *reinterpret_cast<ushort4*>(&outl[(size_t)w * os2 + 4 * l]) = lv;
        } else {
            float4 sv = {r0, r1, r2, r3};
            *reinterpret_cast<float4*>(&out[(size_t)w * os + 4 * l]) = sv;
        }
    }
}

// ================= weight planes: fp32 -> bf16 hi/lo =================
struct WSrc { const float* p[8]; };

__global__ __launch_bounds__(256) void wplanes_kernel(WSrc S,
                                                      unsigned short* __restrict__ ph,
                                                      unsigned short* __restrict__ pl) {
    const int e = blockIdx.x * 256 + threadIdx.x;   // 0..16383
    const int seg = blockIdx.y;
    const int row = e >> 7, k = e & 127;
    float x;
    switch (seg) {
        case 0:  x = (row < 64) ? S.p[0][row * 128 + k] : S.p[1][(row - 64) * 128 + k]; break;
        case 1:  x = (k < 64)   ? S.p[2][row * 64 + k]  : S.p[3][row * 64 + (k - 64)];  break;
        case 2:  x = S.p[4][e]; break;
        case 3:  x = S.p[5][e]; break;
        default: x = (row < 64) ? S.p[6][row * 128 + k] : S.p[7][(row - 64) * 128 + k]; break;
    }
    const unsigned u = __float_as_uint(x);
    const float lo = x - __uint_as_float(u & 0xFFFF0000u);
    const int o = seg * 16384 + e;
    ph[o] = (unsigned short)(u >> 16);
    pl[o] = (unsigned short)(__float_as_uint(lo) >> 16);
}

// ================= MFMA split-bf16 GEMM (128 nodes x 128 cols / block) =================
// APLANES=0: A fp32 (in-register split); APLANES=1: A pre-split hi/lo bf16 planes [NN][128].
// om: 0 = fp32 out; 1 = bf16 out (outp as ushort*); 2 = hi/lo planes (outp hi, outlp lo).
struct GemmArgs {
    const unsigned short* Bh; const unsigned short* Bl;
    float* out0; unsigned short* outl0; const float* bias0; int os0, om0;
    float* out1; unsigned short* outl1; const float* bias1; int os1, om1;
    int relu;
};

template<int APLANES>
__global__ __launch_bounds__(256) void gemm_mfma(
    const float* __restrict__ inf,
    const unsigned short* __restrict__ inh, const unsigned short* __restrict__ inl,
    GemmArgs G) {
    const int t = threadIdx.x;
    const int lane = t & 63;
    const int wid = t >> 6;
    const int wn = wid & 1;
    const int wc = wid >> 1;
    const int l15 = lane & 15;
    const int lk = lane >> 4;
    const int nb = (int)blockIdx.x * 128 + wn * 64;

    float* const outp = wc ? G.out1 : G.out0;
    unsigned short* const outlp = wc ? G.outl1 : G.outl0;
    const float* const biasp = wc ? G.bias1 : G.bias0;
    const int os = wc ? G.os1 : G.os0;
    const int om = wc ? G.om1 : G.om0;
    const unsigned short* const Bhp = G.Bh + (size_t)(wc * 64) * 128;
    const unsigned short* const Blp = G.Bl + (size_t)(wc * 64) * 128;
    const ptrdiff_t dlo = Blp - Bhp;

    float4v acc[4][4];
#pragma unroll
    for (int mi = 0; mi < 4; ++mi)
#pragma unroll
        for (int ci = 0; ci < 4; ++ci) acc[mi][ci] = (float4v)0.0f;

    int arowi[4];
#pragma unroll
    for (int mi = 0; mi < 4; ++mi) {
        int r = nb + mi * 16 + l15;
        arowi[mi] = (r > NN - 1) ? NN - 1 : r;
    }
    const unsigned short* brow[4];
#pragma unroll
    for (int ci = 0; ci < 4; ++ci) brow[ci] = Bhp + (size_t)(ci * 16 + l15) * 128;

    for (int ks = 0; ks < 4; ++ks) {
        const int ko = ks * 32 + lk * 8;
        short8v Ah[4], Al[4];
#pragma unroll
        for (int mi = 0; mi < 4; ++mi) {
            if constexpr (APLANES) {
                const size_t b = (size_t)arowi[mi] * 128 + ko;
                Ah[mi] = *reinterpret_cast<const short8v*>(inh + b);
                Al[mi] = *reinterpret_cast<const short8v*>(inl + b);
            } else {
                const float* ar = inf + (size_t)arowi[mi] * 128;
                const float4v v0 = *reinterpret_cast<const float4v*>(ar + ko);
                const float4v v1 = *reinterpret_cast<const float4v*>(ar + ko + 4);
                float xv[8] = {v0.x, v0.y, v0.z, v0.w, v1.x, v1.y, v1.z, v1.w};
                union { unsigned u[4]; short8v s; } H, L;
#pragma unroll
                for (int q = 0; q < 4; ++q) {
                    const unsigned u0 = __float_as_uint(xv[2 * q]);
                    const unsigned u1 = __float_as_uint(xv[2 * q + 1]);
                    const float l0 = xv[2 * q]     - __uint_as_float(u0 & 0xFFFF0000u);
                    const float l1 = xv[2 * q + 1] - __uint_as_float(u1 & 0xFFFF0000u);
                    H.u[q] = (u1 & 0xFFFF0000u) | (u0 >> 16);
                    L.u[q] = (__float_as_uint(l1) & 0xFFFF0000u) | (__float_as_uint(l0) >> 16);
                }
                Ah[mi] = H.s;
                Al[mi] = L.s;
            }
        }
        short8v Bhf[4], Blf[4];
#pragma unroll
        for (int ci = 0; ci < 4; ++ci) {
            Bhf[ci] = *reinterpret_cast<const short8v*>(brow[ci] + ko);
            Blf[ci] = *reinterpret_cast<const short8v*>(brow[ci] + dlo + ko);
        }
#pragma unroll
        for (int mi = 0; mi < 4; ++mi)
#pragma unroll
            for (int ci = 0; ci < 4; ++ci) {
                acc[mi][ci] = __builtin_amdgcn_mfma_f32_16x16x32_bf16(Ah[mi], Bhf[ci], acc[mi][ci], 0, 0, 0);
                acc[mi][ci] = __builtin_amdgcn_mfma_f32_16x16x32_bf16(Ah[mi], Blf[ci], acc[mi][ci], 0, 0, 0);
                acc[mi][ci] = __builtin_amdgcn_mfma_f32_16x16x32_bf16(Al[mi], Bhf[ci], acc[mi][ci], 0, 0, 0);
            }
    }

#pragma unroll
    for (int ci = 0; ci < 4; ++ci) {
        const int c = ci * 16 + l15;
        const float b = biasp ? biasp[c] : 0.0f;
#pragma unroll
        for (int mi = 0; mi < 4; ++mi) {
#pragma unroll
            for (int j = 0; j < 4; ++j) {
                const int r = nb + mi * 16 + lk * 4 + j;
                if (r < NN) {
                    float v = acc[mi][ci][j] + b;
                    if (G.relu) v = fmaxf(v, 0.0f);
                    if (om == 0) {
                        outp[(size_t)r * os + c] = v;
                    } else if (om == 1) {
                        ((unsigned short*)outp)[(size_t)r * os + c] = f2bf(v);
                    } else {
                        const unsigned short hv = f2bf(v);
                        ((unsigned short*)outp)[(size_t)r * os + c] = hv;
                        outlp[(size_t)r * os + c] = f2bf(v - bf2f(hv));
                    }
                }
            }
        }
    }
}

extern "C" void kernel_launch(void* const* d_in, const int* in_sizes, int n_in,
                              void* d_out, int out_size, void* d_ws, size_t ws_size,
                              hipStream_t stream) {
    const float* x   = (const float*)d_in[0];
    const int*   eix = (const int*)d_in[1];
    const float* Wl1 = (const float*)d_in[2];
    const float* bl1 = (const float*)d_in[3];
    const float* Wr1 = (const float*)d_in[4];
    const float* Wl2 = (const float*)d_in[5];
    const float* bl2 = (const float*)d_in[6];
    const float* Wr2 = (const float*)d_in[7];
    const float* Wl3 = (const float*)d_in[8];
    const float* bl3 = (const float*)d_in[9];
    const float* Wr3 = (const float*)d_in[10];
    const float* Wl4 = (const float*)d_in[11];
    const float* bl4 = (const float*)d_in[12];
    const float* Wr4 = (const float*)d_in[13];
    float* out = (float*)d_out;

    const int* src = eix;        // edge_index[0]
    const int* dst = eix + NE;   // edge_index[1]

    // ---- workspace layout (regions with aliased lifetimes) ----
    char* ws = (char*)d_ws;
    int*   cnt  = (int*)ws;                          // [NN]
    int*   off  = cnt + NN;                          // [NN]
    float* inv  = (float*)(off + NN);                // [NN]
    int*   Hs   = (int*)(inv + NN);                  // [HLEN]
    int*   part = Hs + HLEN;                         // [256]
    unsigned short* srcs = (unsigned short*)(part + 256);  // [NE]
    unsigned short* ph = srcs + NE;                  // [81920]
    unsigned short* pl = ph + 81920;                 // [81920]
    char* R1 = (char*)(pl + 81920);                  // 25.6 MB
    char* R2 = R1 + (size_t)NN * 128 * 4;            // 25.6 MB
    char* R3 = R2 + (size_t)NN * 128 * 4;            // 12.8 MB
    char* R4 = R3 + (size_t)NN * 128 * 2;            // 25.6 MB

    // R1: {XB1 bf16 [NN*64], P1 fp32 [NN*64]} -> {H2h, H2l [NN*128] each}
    unsigned short* XB1 = (unsigned short*)R1;
    float*          P1  = (float*)(R1 + (size_t)NN * 64 * 2);
    unsigned short* H2h = (unsigned short*)R1;
    unsigned short* H2l = H2h + (size_t)NN * 128;
    // R2: {HCh, HCl [NN*128]} -> {H3h, H3l [NN*128]}
    unsigned short* HCh = (unsigned short*)R2;
    unsigned short* HCl = HCh + (size_t)NN * 128;
    unsigned short* H3h = HCh;
    unsigned short* H3l = HCl;
    // R3: {G3B bf16 [NN*128]} -> {G4B bf16 [NN*64]}
    unsigned short* G3B = (unsigned short*)R3;
    unsigned short* G4B = (unsigned short*)R3;
    // R4: {tmp [NE] u32 (CSR only)} -> {HPRE fp32 [NN*128]}
    unsigned* tmp  = (unsigned*)R4;
    float*    HPRE = (float*)R4;

    // ---- radix CSR build ----
    hist_kernel<<<PB, 256, 0, stream>>>(dst, Hs);
    scanA_kernel<<<SAB, 256, 0, stream>>>(Hs, part);
    scanB_kernel<<<1, 128, 0, stream>>>(part);
    scanC_kernel<<<SAB, 256, 0, stream>>>(Hs, part);
    partition_kernel<<<PB, 256, 0, stream>>>(src, dst, Hs, tmp);
    finalize_kernel<<<NBUK, 256, 0, stream>>>(tmp, Hs, off, cnt, inv, srcs);

    // ---- weight bf16 hi/lo planes ----
    {
        WSrc s;
        s.p[0] = Wl1; s.p[1] = Wr1; s.p[2] = Wl2; s.p[3] = Wr2;
        s.p[4] = Wl3; s.p[5] = Wr3; s.p[6] = Wl4; s.p[7] = Wr4;
        wplanes_kernel<<<dim3(64, 5), 256, 0, stream>>>(s, ph, pl);
    }

    // ---- Layer 1: x@[Wl1;Wr1] -> XB1 (bf16 msgs), P1 (h1pre fp32 +bl1) ----
    {
        GemmArgs a{ph, pl,
                   (float*)XB1, nullptr, nullptr, 64, 1,
                   P1, nullptr, bl1, 64, 0, 0};
        gemm_mfma<0><<<GB, 256, 0, stream>>>(x, nullptr, nullptr, a);
    }
    // h1 = relu(P1 + mean(XB1)) -> planes HCh/HCl cols 64..127
    gather_kernel<64, 1, 1><<<12500, 256, 0, stream>>>(
        XB1, 64, srcs, off, cnt, inv, P1, 64, nullptr, 0, HCh + 64, HCl + 64, 128);

    // ---- Layer 2: mean(h1) -> planes cols 0..63; [mean|h1]@[Wl2|Wr2] -> H2 planes (relu) ----
    gather_kernel<64, 0, 1><<<12500, 256, 0, stream>>>(
        HCh + 64, 128, srcs, off, cnt, inv, nullptr, 0, nullptr, 0, HCh, HCl, 128);
    {
        GemmArgs a{ph + 16384, pl + 16384,
                   (float*)H2h, H2l, bl2, 128, 2,
                   (float*)(H2h + 64), H2l + 64, bl2 + 64, 128, 2, 1};
        gemm_mfma<1><<<GB, 256, 0, stream>>>(nullptr, HCh, HCl, a);
    }

    // ---- Layer 3: h2@Wl3 -> G3B (bf16 msgs); h2@Wr3+bl3 -> HPRE (fp32) ----
    {
        GemmArgs a{ph + 2 * 16384, pl + 2 * 16384,
                   (float*)G3B, nullptr, nullptr, 128, 1,
                   (float*)(G3B + 64), nullptr, nullptr, 128, 1, 0};
        gemm_mfma<1><<<GB, 256, 0, stream>>>(nullptr, H2h, H2l, a);
    }
    {
        GemmArgs a{ph + 3 * 16384, pl + 3 * 16384,
                   HPRE, nullptr, bl3, 128, 0,
                   HPRE + 64, nullptr, bl3 + 64, 128, 0, 0};
        gemm_mfma<1><<<GB, 256, 0, stream>>>(nullptr, H2h, H2l, a);
    }
    // h3 = relu(HPRE + mean(G3B)) -> planes H3h/H3l
    gather_kernel<128, 1, 1><<<12500, 256, 0, stream>>>(
        G3B, 128, srcs, off, cnt, inv, HPRE, 128, nullptr, 0, H3h, H3l, 128);

    // ---- Layer 4: h3@Wl4 -> G4B (bf16 msgs); h3@Wr4+bl4 -> d_out; gather -> out ----
    {
        GemmArgs a{ph + 4 * 16384, pl + 4 * 16384,
                   (float*)G4B, nullptr, nullptr, 64, 1,
                   out, nullptr, bl4, 64, 0, 0};
        gemm_mfma<1><<<GB, 256, 0, stream>>>(nullptr, H3h, H3l, a);
    }
    gather_kernel<64, 2, 0><<<12500, 256, 0, stream>>>(
        G4B, 64, srcs, off, cnt, inv, out, 64, out, 64, nullptr, nullptr, 0);
}